// Round 3
// baseline (2604.497 us; speedup 1.0000x reference)
//
#include <hip/hip_runtime.h>

#define B 8
#define N 100000
#define NE 3200000

// Static device-side scratch: no dependence on ws_size, no runtime API calls
// inside kernel_launch (graph-capture safe by construction).
__device__ float g_net[B * N];   // net_flows accumulator (B, N)
__device__ float g_accum;        // continuity sum accumulator

// ---------------------------------------------------------------------------
// Kernel 0: zero the scratch (runs every call; no state carried across calls).
// ---------------------------------------------------------------------------
__global__ __launch_bounds__(256) void zero_kernel() {
    int i = blockIdx.x * blockDim.x + threadIdx.x;
    if (i < B * N) g_net[i] = 0.0f;
    if (i == 0) g_accum = 0.0f;
}

// ---------------------------------------------------------------------------
// Kernel 1: per-edge flow compute + scatter-add into net_flows.
// One thread per edge; batch loop in registers so edge_index/edge_attr are
// read exactly once instead of 8x.
// NOTE: harness delivers integer inputs as int32 (NOT int64) — const int*.
// ---------------------------------------------------------------------------
__global__ __launch_bounds__(256) void edge_kernel(
    const float* __restrict__ node_heads,   // (B, N)
    const int* __restrict__ edge_index,     // (2, E) int32
    const float* __restrict__ edge_attr,    // (E, 2)
    float* __restrict__ flows_out)          // (B, E)  (d_out + 3)
{
    int e = blockIdx.x * blockDim.x + threadIdx.x;
    if (e >= NE) return;

    int s = edge_index[e];
    int d = edge_index[NE + e];
    float c = ((const float2*)edge_attr)[e].x;  // coalesced 8B load, col 0

#pragma unroll
    for (int b = 0; b < B; ++b) {
        float hs = node_heads[b * N + s];   // 3.2 MB table -> mostly L2 hits
        float hd = node_heads[b * N + d];
        float f = c * (hs - hd);
        flows_out[b * NE + e] = f;          // coalesced store
        unsafeAtomicAdd(&g_net[b * N + s], f);   // native global_atomic_add_f32
        unsafeAtomicAdd(&g_net[b * N + d], -f);
    }
}

// ---------------------------------------------------------------------------
// Kernel 2: continuity = sum((net - demands)^2) over B*N, one atomic/block.
// ---------------------------------------------------------------------------
__global__ __launch_bounds__(256) void cont_kernel(
    const float* __restrict__ demands)
{
    __shared__ float ssum[4];
    float local = 0.0f;
    int stride = gridDim.x * blockDim.x;
    for (int i = blockIdx.x * blockDim.x + threadIdx.x; i < B * N; i += stride) {
        float v = g_net[i] - demands[i];
        local = fmaf(v, v, local);
    }
    // wave64 shuffle reduce
    for (int off = 32; off > 0; off >>= 1)
        local += __shfl_down(local, off, 64);
    int lane = threadIdx.x & 63;
    int wave = threadIdx.x >> 6;
    if (lane == 0) ssum[wave] = local;
    __syncthreads();
    if (threadIdx.x == 0) {
        float t = ssum[0] + ssum[1] + ssum[2] + ssum[3];
        atomicAdd(&g_accum, t);
    }
}

// ---------------------------------------------------------------------------
// Kernel 3: boundary loss (B x 64 gathers) + finalize the 3 scalars.
// ---------------------------------------------------------------------------
__global__ __launch_bounds__(512) void finalize_kernel(
    const float* __restrict__ node_heads,
    const int* __restrict__ res_nodes,      // (64,) int32
    const float* __restrict__ res_head,     // (1,)
    float* __restrict__ out)
{
    __shared__ float ssum[8];
    int t = threadIdx.x;          // 512 = B*64
    int b = t >> 6;
    int j = t & 63;
    float pred = node_heads[b * N + res_nodes[j]];
    float diff = pred - res_head[0];
    float local = diff * diff;
    for (int off = 32; off > 0; off >>= 1)
        local += __shfl_down(local, off, 64);
    if ((t & 63) == 0) ssum[t >> 6] = local;
    __syncthreads();
    if (t == 0) {
        float bsum = 0.0f;
        for (int w = 0; w < 8; ++w) bsum += ssum[w];
        float boundary = bsum / 512.0f;                 // mean over B*64
        float continuity = g_accum / (float)(B * N);    // mean over B*N
        out[0] = continuity;
        out[1] = boundary;
        out[2] = continuity + boundary;                 // LAMBDA_PHYSICS = 1.0
    }
}

extern "C" void kernel_launch(void* const* d_in, const int* in_sizes, int n_in,
                              void* d_out, int out_size, void* d_ws, size_t ws_size,
                              hipStream_t stream) {
    const float* node_heads = (const float*)d_in[0];
    const float* demands    = (const float*)d_in[1];
    const int*   edge_index = (const int*)d_in[2];    // int32 per harness
    const float* edge_attr  = (const float*)d_in[3];
    const int*   res_nodes  = (const int*)d_in[4];    // int32 per harness
    const float* res_head   = (const float*)d_in[5];

    float* out = (float*)d_out;   // [cont, bound, total, flows(B,E)]

    zero_kernel<<<(B * N + 255) / 256, 256, 0, stream>>>();

    edge_kernel<<<(NE + 255) / 256, 256, 0, stream>>>(
        node_heads, edge_index, edge_attr, out + 3);

    cont_kernel<<<1024, 256, 0, stream>>>(demands);

    finalize_kernel<<<1, 512, 0, stream>>>(node_heads, res_nodes, res_head, out);
}

// Round 4
// 676.042 us; speedup vs baseline: 3.8526x; 3.8526x over previous
//
#include <hip/hip_runtime.h>

#define B 8
#define N 100000
#define NE 3200000
#define CHUNK_LOG 11
#define CHUNK 2048            // nodes per chunk (LDS acc = 2048*8*4 = 64 KB)
#define NCHUNK 49             // ceil(N / CHUNK)
#define CAP 140000            // per-bucket record capacity (expect ~130.6k +- 0.4k)
#define SEG 8                 // phase-2 blocks per chunk
#define EPB 4096              // phase-1 edges per block

struct Rec { int me; int other; float c; };   // 12 B endpoint record

// Static device scratch (graph-capture safe; recomputed fully every call).
__device__ Rec   g_rec[(size_t)NCHUNK * CAP];                    // 82.3 MB
__device__ int   g_cursor[NCHUNK];
__device__ float g_heads_t[N * B];                               // node-major heads
__device__ float g_partial[(size_t)NCHUNK * SEG * CHUNK * B];    // 25.7 MB
__device__ float g_accum;

// ---------------------------------------------------------------------------
__global__ __launch_bounds__(64) void zero_kernel() {
    int i = threadIdx.x;
    if (i < NCHUNK) g_cursor[i] = 0;
    if (i == 0) g_accum = 0.0f;
}

// heads (B,N) -> heads_t (N,B): each node's 8 batch values contiguous (32 B).
__global__ __launch_bounds__(256) void transpose_kernel(
    const float* __restrict__ node_heads)
{
    int i = blockIdx.x * blockDim.x + threadIdx.x;   // i = n*8 + b
    if (i >= N * B) return;
    int n = i >> 3, b = i & 7;
    g_heads_t[i] = node_heads[b * N + n];
}

// ---------------------------------------------------------------------------
// Phase 1: flows output + bucket endpoint records by node chunk.
// Contribution to node `me` is c*(h[me]-h[other]) for BOTH endpoints
// (src: +f = c*(h_s-h_d); dst: -f = c*(h_d-h_s)) -> uniform record.
// ---------------------------------------------------------------------------
__global__ __launch_bounds__(256) void phase1_kernel(
    const int* __restrict__ edge_index,     // (2, E) int32
    const float* __restrict__ edge_attr,    // (E, 2)
    float* __restrict__ flows_out)          // (B, E)
{
    __shared__ int s_s[EPB];
    __shared__ int s_d[EPB];
    __shared__ int hist[NCHUNK];
    int tid = threadIdx.x;
    int e0 = blockIdx.x * EPB;

    for (int i = tid; i < NCHUNK; i += 256) hist[i] = 0;
    __syncthreads();

    // pass A: block histogram of endpoint chunks; stage indices in LDS
#pragma unroll
    for (int i = 0; i < EPB / 256; ++i) {
        int idx = i * 256 + tid;
        int e = e0 + idx;
        int s = -1, d = -1;
        if (e < NE) {
            s = edge_index[e];
            d = edge_index[NE + e];
            atomicAdd(&hist[s >> CHUNK_LOG], 1);
            atomicAdd(&hist[d >> CHUNK_LOG], 1);
        }
        s_s[idx] = s;
        s_d[idx] = d;
    }
    __syncthreads();

    // reserve per-bucket space: ~NCHUNK global atomics per block
    for (int i = tid; i < NCHUNK; i += 256)
        hist[i] = atomicAdd(&g_cursor[i], hist[i]);   // hist -> running cursor
    __syncthreads();

    // pass B: compute flows, emit records
#pragma unroll
    for (int i = 0; i < EPB / 256; ++i) {
        int idx = i * 256 + tid;
        int e = e0 + idx;
        if (e >= NE) continue;
        int s = s_s[idx];
        int d = s_d[idx];
        float c = ((const float2*)edge_attr)[e].x;

        const float4* hs4 = (const float4*)&g_heads_t[s << 3];
        const float4* hd4 = (const float4*)&g_heads_t[d << 3];
        float4 a0 = hs4[0], a1 = hs4[1];
        float4 b0 = hd4[0], b1 = hd4[1];
        flows_out[0 * NE + e] = c * (a0.x - b0.x);
        flows_out[1 * NE + e] = c * (a0.y - b0.y);
        flows_out[2 * NE + e] = c * (a0.z - b0.z);
        flows_out[3 * NE + e] = c * (a0.w - b0.w);
        flows_out[4 * NE + e] = c * (a1.x - b1.x);
        flows_out[5 * NE + e] = c * (a1.y - b1.y);
        flows_out[6 * NE + e] = c * (a1.z - b1.z);
        flows_out[7 * NE + e] = c * (a1.w - b1.w);

        int ks = s >> CHUNK_LOG;
        int ps = atomicAdd(&hist[ks], 1);
        if (ps < CAP) { Rec r; r.me = s; r.other = d; r.c = c;
                        g_rec[(size_t)ks * CAP + ps] = r; }
        int kd = d >> CHUNK_LOG;
        int pd = atomicAdd(&hist[kd], 1);
        if (pd < CAP) { Rec r; r.me = d; r.other = s; r.c = c;
                        g_rec[(size_t)kd * CAP + pd] = r; }
    }
}

// ---------------------------------------------------------------------------
// Phase 2: per (chunk, segment) block LDS-accumulate records -> partials.
// ---------------------------------------------------------------------------
__global__ __launch_bounds__(256) void phase2_kernel() {
    __shared__ float acc[CHUNK * B];    // exactly 64 KB
    int chunk = blockIdx.x / SEG;
    int seg   = blockIdx.x % SEG;

    for (int i = threadIdx.x; i < CHUNK * B; i += 256) acc[i] = 0.0f;
    __syncthreads();

    int cnt = g_cursor[chunk];
    if (cnt > CAP) cnt = CAP;
    size_t rbase = (size_t)chunk * CAP;

    for (int r = seg * 256 + threadIdx.x; r < cnt; r += SEG * 256) {
        Rec rec = g_rec[rbase + r];
        int ml = (rec.me & (CHUNK - 1)) << 3;
        const float4* hm4 = (const float4*)&g_heads_t[rec.me << 3];
        const float4* ho4 = (const float4*)&g_heads_t[rec.other << 3];
        float4 a0 = hm4[0], a1 = hm4[1];
        float4 b0 = ho4[0], b1 = ho4[1];
        atomicAdd(&acc[ml + 0], rec.c * (a0.x - b0.x));
        atomicAdd(&acc[ml + 1], rec.c * (a0.y - b0.y));
        atomicAdd(&acc[ml + 2], rec.c * (a0.z - b0.z));
        atomicAdd(&acc[ml + 3], rec.c * (a0.w - b0.w));
        atomicAdd(&acc[ml + 4], rec.c * (a1.x - b1.x));
        atomicAdd(&acc[ml + 5], rec.c * (a1.y - b1.y));
        atomicAdd(&acc[ml + 6], rec.c * (a1.z - b1.z));
        atomicAdd(&acc[ml + 7], rec.c * (a1.w - b1.w));
    }
    __syncthreads();

    float* out = &g_partial[(size_t)blockIdx.x * (CHUNK * B)];
    for (int i = threadIdx.x; i < CHUNK * B; i += 256) out[i] = acc[i];
}

// ---------------------------------------------------------------------------
// Merge partials + fused continuity reduction (no net buffer needed).
// ---------------------------------------------------------------------------
__global__ __launch_bounds__(256) void merge_cont_kernel(
    const float* __restrict__ demands)
{
    __shared__ float ssum[4];
    float local = 0.0f;
    int stride = gridDim.x * blockDim.x;
    for (int i = blockIdx.x * blockDim.x + threadIdx.x; i < N * B; i += stride) {
        int n = i >> 3, b = i & 7;
        int chunk = n >> CHUNK_LOG;
        int loc = ((n & (CHUNK - 1)) << 3) + b;
        float v = 0.0f;
#pragma unroll
        for (int s = 0; s < SEG; ++s)
            v += g_partial[(size_t)(chunk * SEG + s) * (CHUNK * B) + loc];
        v -= demands[b * N + n];
        local = fmaf(v, v, local);
    }
    for (int off = 32; off > 0; off >>= 1)
        local += __shfl_down(local, off, 64);
    int lane = threadIdx.x & 63, wave = threadIdx.x >> 6;
    if (lane == 0) ssum[wave] = local;
    __syncthreads();
    if (threadIdx.x == 0)
        unsafeAtomicAdd(&g_accum, ssum[0] + ssum[1] + ssum[2] + ssum[3]);
}

// ---------------------------------------------------------------------------
// Boundary loss + finalize scalars.
// ---------------------------------------------------------------------------
__global__ __launch_bounds__(512) void finalize_kernel(
    const float* __restrict__ node_heads,
    const int* __restrict__ res_nodes,      // (64,) int32
    const float* __restrict__ res_head,     // (1,)
    float* __restrict__ out)
{
    __shared__ float ssum[8];
    int t = threadIdx.x;          // 512 = B*64
    int b = t >> 6;
    int j = t & 63;
    float pred = node_heads[b * N + res_nodes[j]];
    float diff = pred - res_head[0];
    float local = diff * diff;
    for (int off = 32; off > 0; off >>= 1)
        local += __shfl_down(local, off, 64);
    if ((t & 63) == 0) ssum[t >> 6] = local;
    __syncthreads();
    if (t == 0) {
        float bsum = 0.0f;
        for (int w = 0; w < 8; ++w) bsum += ssum[w];
        float boundary = bsum / 512.0f;
        float continuity = g_accum / (float)(B * N);
        out[0] = continuity;
        out[1] = boundary;
        out[2] = continuity + boundary;     // LAMBDA_PHYSICS = 1.0
    }
}

extern "C" void kernel_launch(void* const* d_in, const int* in_sizes, int n_in,
                              void* d_out, int out_size, void* d_ws, size_t ws_size,
                              hipStream_t stream) {
    const float* node_heads = (const float*)d_in[0];
    const float* demands    = (const float*)d_in[1];
    const int*   edge_index = (const int*)d_in[2];    // int32 per harness
    const float* edge_attr  = (const float*)d_in[3];
    const int*   res_nodes  = (const int*)d_in[4];    // int32 per harness
    const float* res_head   = (const float*)d_in[5];

    float* out = (float*)d_out;   // [cont, bound, total, flows(B,E)]

    zero_kernel<<<1, 64, 0, stream>>>();
    transpose_kernel<<<(N * B + 255) / 256, 256, 0, stream>>>(node_heads);
    phase1_kernel<<<(NE + EPB - 1) / EPB, 256, 0, stream>>>(
        edge_index, edge_attr, out + 3);
    phase2_kernel<<<NCHUNK * SEG, 256, 0, stream>>>();
    merge_cont_kernel<<<1024, 256, 0, stream>>>(demands);
    finalize_kernel<<<1, 512, 0, stream>>>(node_heads, res_nodes, res_head, out);
}